// Round 1
// baseline (1286.613 us; speedup 1.0000x reference)
//
#include <hip/hip_runtime.h>
#include <hip/hip_bf16.h>
#include <math.h>

#define CA 768
#define CS 384
#define CZ 128
#define NH 16
#define HD 48
#define BB 2
#define SS 768
#define NROW (BB*SS)

constexpr float EPS = 1e-5f;
constexpr float QSCALE = 0.14433756729740643f; // 1/sqrt(48)

__device__ __forceinline__ float sigmoidf_(float x) { return 1.f/(1.f + expf(-x)); }

// ---------------------------------------------------------------------------
// K1: row LayerNorms: sn = LN(s)*gamma_s ; lna = LN(a) (no affine)
// ---------------------------------------------------------------------------
__global__ __launch_bounds__(256) void ln_kernel(
    const float* __restrict__ s, const float* __restrict__ a,
    const float* __restrict__ gamma_s,
    float* __restrict__ sn, float* __restrict__ lna)
{
  int row = blockIdx.x;
  int t = threadIdx.x;
  __shared__ float red[8];
  int wid = t >> 6;

  // ---- s row (384) ----
  const float* sr = s + (size_t)row*CS;
  float x0 = sr[t];                       // t<256<384 always valid
  float x1 = (t < CS-256) ? sr[256+t] : 0.f;
  float sum = x0 + x1;
  float sq  = x0*x0 + x1*x1;
  for (int o = 32; o; o >>= 1) { sum += __shfl_xor(sum, o); sq += __shfl_xor(sq, o); }
  if ((t & 63) == 0) { red[wid] = sum; red[4+wid] = sq; }
  __syncthreads();
  sum = red[0]+red[1]+red[2]+red[3];
  sq  = red[4]+red[5]+red[6]+red[7];
  float mu = sum * (1.f/CS);
  float var = sq * (1.f/CS) - mu*mu;
  float rstd = rsqrtf(var + EPS);
  sn[(size_t)row*CS + t] = (x0 - mu)*rstd*gamma_s[t];
  if (t < CS-256) sn[(size_t)row*CS + 256 + t] = (x1 - mu)*rstd*gamma_s[256+t];
  __syncthreads();

  // ---- a row (768) ----
  const float* ar = a + (size_t)row*CA;
  float y0 = ar[t], y1 = ar[256+t], y2 = ar[512+t];
  sum = y0+y1+y2; sq = y0*y0 + y1*y1 + y2*y2;
  for (int o = 32; o; o >>= 1) { sum += __shfl_xor(sum, o); sq += __shfl_xor(sq, o); }
  if ((t & 63) == 0) { red[wid] = sum; red[4+wid] = sq; }
  __syncthreads();
  sum = red[0]+red[1]+red[2]+red[3];
  sq  = red[4]+red[5]+red[6]+red[7];
  mu = sum*(1.f/CA); var = sq*(1.f/CA) - mu*mu; rstd = rsqrtf(var + EPS);
  lna[(size_t)row*CA + t]       = (y0-mu)*rstd;
  lna[(size_t)row*CA + 256 + t] = (y1-mu)*rstd;
  lna[(size_t)row*CA + 512 + t] = (y2-mu)*rstd;
}

// ---------------------------------------------------------------------------
// Unified tiled fp32 GEMM, 64x64 tile, 4x4 per thread, K-tile 32.
// mode = mode0 + blockIdx.z:
//   0: an = sigmoid(sn@Wada_g + b)*lna + sn@Wada_o        (dual-B, K=384)
//   1: gate = sigmoid(s@Wsg + bsg)                        (K=384)
//   2: q = (an@Wq + bq)*QSCALE  -> [b,h,i,d]
//   3: k = an@Wk                -> [b,h,i,d]
//   4: v = an@Wv                -> [b,h,i,d]
//   5: g = sigmoid(an@Wg)       -> row-major
//   6: out = ((g .* o)@Wout) .* gate -> d_out
// ---------------------------------------------------------------------------
__global__ __launch_bounds__(256) void gemm_kernel(int mode0,
    const float* __restrict__ sn, const float* __restrict__ s_in,
    const float* __restrict__ an_in, const float* __restrict__ g_in,
    const float* __restrict__ o_in, const float* __restrict__ lna,
    const float* __restrict__ gate_in,
    const float* __restrict__ Wada_g, const float* __restrict__ Wada_o,
    const float* __restrict__ bada_g,
    const float* __restrict__ Wsg, const float* __restrict__ bsg,
    const float* __restrict__ Wq, const float* __restrict__ bq,
    const float* __restrict__ Wk, const float* __restrict__ Wv,
    const float* __restrict__ Wg, const float* __restrict__ Wout,
    float* __restrict__ an_out, float* __restrict__ gate_out,
    float* __restrict__ q_out, float* __restrict__ k_out,
    float* __restrict__ v_out, float* __restrict__ g_out,
    float* __restrict__ final_out)
{
  int mode = mode0 + (int)blockIdx.z;
  const float* A; const float* B0; const float* B1 = nullptr; int K;
  switch (mode) {
    case 0: A = sn;    B0 = Wada_g; B1 = Wada_o; K = CS; break;
    case 1: A = s_in;  B0 = Wsg;  K = CS; break;
    case 2: A = an_in; B0 = Wq;   K = CA; break;
    case 3: A = an_in; B0 = Wk;   K = CA; break;
    case 4: A = an_in; B0 = Wv;   K = CA; break;
    case 5: A = an_in; B0 = Wg;   K = CA; break;
    default: A = g_in; B0 = Wout; K = CA; break;
  }
  const int m0 = blockIdx.y*64, n0 = blockIdx.x*64;
  const int t = threadIdx.x;
  __shared__ __align__(16) float As[32][64];
  __shared__ __align__(16) float Bs0[32][64];
  __shared__ __align__(16) float Bs1[32][64];
  float acc[4][4];
  float acc2[4][4];
#pragma unroll
  for (int i=0;i<4;i++)
#pragma unroll
    for (int j=0;j<4;j++){ acc[i][j]=0.f; acc2[i][j]=0.f; }

  const int tm = t >> 4, tn = t & 15;
  const int am = t & 63, akq = t >> 6;     // A staging: row am, k-offset akq*8
  const int bkr = t >> 3, bn = (t & 7)*8;  // B staging: k-row bkr, n-offset bn
  const bool dual = (mode == 0);
  const bool amul = (mode == 6);

  for (int k0 = 0; k0 < K; k0 += 32) {
    __syncthreads();
    {
      float4 a04, a14;
      const size_t arow = (size_t)(m0 + am)*K;
      if (amul) {
        int m = m0 + am;
        int bI = (m >= SS) ? 1 : 0;
        int irow = m - bI*SS;
        int kb0 = k0 + akq*8;
        int h0 = kb0/HD, d0 = kb0 - h0*HD;
        int kb1 = kb0 + 4;
        int h1 = kb1/HD, d1 = kb1 - h1*HD;
        float4 g0 = *(const float4*)(A + arow + kb0);
        float4 g1 = *(const float4*)(A + arow + kb1);
        float4 o0 = *(const float4*)(o_in + ((size_t)(bI*NH + h0)*SS + irow)*HD + d0);
        float4 o1 = *(const float4*)(o_in + ((size_t)(bI*NH + h1)*SS + irow)*HD + d1);
        a04 = make_float4(g0.x*o0.x, g0.y*o0.y, g0.z*o0.z, g0.w*o0.w);
        a14 = make_float4(g1.x*o1.x, g1.y*o1.y, g1.z*o1.z, g1.w*o1.w);
      } else {
        const float* ap = A + arow + k0 + akq*8;
        a04 = *(const float4*)ap;
        a14 = *(const float4*)(ap+4);
      }
      const int kk = akq*8;
      As[kk+0][am]=a04.x; As[kk+1][am]=a04.y; As[kk+2][am]=a04.z; As[kk+3][am]=a04.w;
      As[kk+4][am]=a14.x; As[kk+5][am]=a14.y; As[kk+6][am]=a14.z; As[kk+7][am]=a14.w;
    }
    {
      const float* bp = B0 + (size_t)(k0 + bkr)*CA + n0 + bn;
      *(float4*)&Bs0[bkr][bn]   = *(const float4*)bp;
      *(float4*)&Bs0[bkr][bn+4] = *(const float4*)(bp+4);
      if (dual) {
        const float* bp1 = B1 + (size_t)(k0 + bkr)*CA + n0 + bn;
        *(float4*)&Bs1[bkr][bn]   = *(const float4*)bp1;
        *(float4*)&Bs1[bkr][bn+4] = *(const float4*)(bp1+4);
      }
    }
    __syncthreads();
    if (dual) {
      for (int kk = 0; kk < 32; kk++) {
        float a_[4], b_[4], c_[4];
        *(float4*)a_ = *(float4*)&As[kk][tm*4];
        *(float4*)b_ = *(float4*)&Bs0[kk][tn*4];
        *(float4*)c_ = *(float4*)&Bs1[kk][tn*4];
#pragma unroll
        for (int i=0;i<4;i++)
#pragma unroll
          for (int j=0;j<4;j++){
            acc[i][j]  = fmaf(a_[i], b_[j], acc[i][j]);
            acc2[i][j] = fmaf(a_[i], c_[j], acc2[i][j]);
          }
      }
    } else {
      for (int kk = 0; kk < 32; kk++) {
        float a_[4], b_[4];
        *(float4*)a_ = *(float4*)&As[kk][tm*4];
        *(float4*)b_ = *(float4*)&Bs0[kk][tn*4];
#pragma unroll
        for (int i=0;i<4;i++)
#pragma unroll
          for (int j=0;j<4;j++)
            acc[i][j] = fmaf(a_[i], b_[j], acc[i][j]);
      }
    }
  }

  // epilogue
  const int nc0 = n0 + tn*4;
#pragma unroll
  for (int i = 0; i < 4; i++) {
    int m = m0 + tm*4 + i;
    int bI = (m >= SS) ? 1 : 0;
    int irow = m - bI*SS;
    float4 res;
    float* rp = (float*)&res;
    if (mode == 0) {
#pragma unroll
      for (int j=0;j<4;j++){
        float garg = acc[i][j] + bada_g[nc0+j];
        float sig = sigmoidf_(garg);
        rp[j] = fmaf(sig, lna[(size_t)m*CA + nc0 + j], acc2[i][j]);
      }
      *(float4*)(an_out + (size_t)m*CA + nc0) = res;
    } else if (mode == 1) {
#pragma unroll
      for (int j=0;j<4;j++) rp[j] = sigmoidf_(acc[i][j] + bsg[nc0+j]);
      *(float4*)(gate_out + (size_t)m*CA + nc0) = res;
    } else if (mode == 2) {
      int h = nc0/HD, d = nc0 - h*HD;
#pragma unroll
      for (int j=0;j<4;j++) rp[j] = (acc[i][j] + bq[nc0+j])*QSCALE;
      *(float4*)(q_out + ((size_t)(bI*NH + h)*SS + irow)*HD + d) = res;
    } else if (mode == 3) {
      int h = nc0/HD, d = nc0 - h*HD;
#pragma unroll
      for (int j=0;j<4;j++) rp[j] = acc[i][j];
      *(float4*)(k_out + ((size_t)(bI*NH + h)*SS + irow)*HD + d) = res;
    } else if (mode == 4) {
      int h = nc0/HD, d = nc0 - h*HD;
#pragma unroll
      for (int j=0;j<4;j++) rp[j] = acc[i][j];
      *(float4*)(v_out + ((size_t)(bI*NH + h)*SS + irow)*HD + d) = res;
    } else if (mode == 5) {
#pragma unroll
      for (int j=0;j<4;j++) rp[j] = sigmoidf_(acc[i][j]);
      *(float4*)(g_out + (size_t)m*CA + nc0) = res;
    } else {
#pragma unroll
      for (int j=0;j<4;j++) rp[j] = acc[i][j]*gate_in[(size_t)m*CA + nc0 + j];
      *(float4*)(final_out + (size_t)m*CA + nc0) = res;
    }
  }
}

// ---------------------------------------------------------------------------
// K3: pair bias. bias_t[b,h,i,j] = (LN(z[b,j,i,:])*gz+bz)@Wb[:,h] + beta[b,j,i,h]
// One z read: out = rstd*acc - rstd*mu*SG + SB + beta, acc = z·(gz⊙Wb).
// Thread (tx,ty): x = j index (fast, coalesced store), y = i index.
// ---------------------------------------------------------------------------
__global__ __launch_bounds__(256) void bias_kernel(
    const float* __restrict__ z, const float* __restrict__ beta,
    const float* __restrict__ Wb, const float* __restrict__ gz,
    const float* __restrict__ bz, float* __restrict__ bias_t)
{
  __shared__ __align__(16) float GT[16][128];  // GT[h][c] = gz[c]*Wb[c][h]
  __shared__ float SGs[16], SBs[16];
  int t = threadIdx.x;
  for (int idx = t; idx < 2048; idx += 256) {
    int c = idx >> 4, h = idx & 15;
    GT[h][c] = gz[c]*Wb[c*16 + h];
  }
  __syncthreads();
  if (t < 16) {
    float sg = 0.f, sb = 0.f;
    for (int c = 0; c < 128; c++) { sg += GT[t][c]; sb += bz[c]*Wb[c*16 + t]; }
    SGs[t] = sg; SBs[t] = sb;
  }
  __syncthreads();

  int tx = t & 15, ty = t >> 4;
  int b = blockIdx.z;
  int x = blockIdx.x*16 + tx;   // z first S index (= logits j)
  int y = blockIdx.y*16 + ty;   // z second S index (= logits i)
  const float* zrow = z + (((size_t)b*SS + x)*SS + y)*CZ;

  float acc[16];
#pragma unroll
  for (int h=0;h<16;h++) acc[h]=0.f;
  float sum=0.f, sq=0.f;
#pragma unroll 4
  for (int c4 = 0; c4 < 32; c4++) {
    float4 z4 = *(const float4*)(zrow + c4*4);
    sum += (z4.x+z4.y)+(z4.z+z4.w);
    sq = fmaf(z4.x,z4.x, fmaf(z4.y,z4.y, fmaf(z4.z,z4.z, fmaf(z4.w,z4.w, sq))));
#pragma unroll
    for (int h=0;h<16;h++){
      float4 g4 = *(const float4*)&GT[h][c4*4];   // uniform address -> broadcast
      acc[h] = fmaf(z4.x,g4.x, fmaf(z4.y,g4.y, fmaf(z4.z,g4.z, fmaf(z4.w,g4.w, acc[h]))));
    }
  }
  float mu = sum*(1.f/128.f);
  float var = sq*(1.f/128.f) - mu*mu;
  float rstd = rsqrtf(var + EPS);
  float mrs = -mu*rstd;

  const float* bp = beta + (((size_t)b*SS + x)*SS + y)*NH;
  float bb[16];
#pragma unroll
  for (int q4 = 0; q4 < 4; q4++) {
    float4 b4 = *(const float4*)(bp + q4*4);
    bb[q4*4+0]=b4.x; bb[q4*4+1]=b4.y; bb[q4*4+2]=b4.z; bb[q4*4+3]=b4.w;
  }
  size_t obase = (((size_t)b*NH)*SS + y)*SS + x;
#pragma unroll
  for (int h=0;h<16;h++){
    float val = fmaf(rstd, acc[h], fmaf(mrs, SGs[h], SBs[h])) + bb[h];
    bias_t[obase + (size_t)h*SS*SS] = val;
  }
}

// ---------------------------------------------------------------------------
// K4: flash attention. Block: (b,h, 64-row i-tile); wave: 16 rows.
// Lane (r=l&15, quad=l>>4): S-phase owns j-chunk quad*16..+15; PV owns
// d-chunk quad*12..+11 (p exchanged through p_lds[j][r], bank-clean).
// ---------------------------------------------------------------------------
__global__ __launch_bounds__(256) void attn_kernel(
    const float* __restrict__ q_ws, const float* __restrict__ k_ws,
    const float* __restrict__ v_ws, const float* __restrict__ bias_t,
    float* __restrict__ o_ws)
{
  __shared__ __align__(16) float q_lds[64][52];
  __shared__ __align__(16) float kT[48][64];
  __shared__ __align__(16) float v_lds[64][48];
  __shared__ float p_lds[4][64][17];

  int t = threadIdx.x;
  int i0 = blockIdx.x*64;
  size_t bh = (size_t)(blockIdx.z*NH + blockIdx.y);
  const float* qbase = q_ws + (bh*SS + i0)*HD;
  for (int f = t; f < 64*12; f += 256) {
    int r = f/12, dc = (f - r*12)*4;
    *(float4*)&q_lds[r][dc] = *(const float4*)(qbase + r*HD + dc);
  }
  int w = t >> 6, l = t & 63;
  int r = l & 15, quad = l >> 4;
  int row = w*16 + r;

  float m_i = -INFINITY, l_i = 0.f;
  float oacc[12];
#pragma unroll
  for (int ii=0;ii<12;ii++) oacc[ii]=0.f;

  const float* kbase = k_ws + bh*SS*HD;
  const float* vbase = v_ws + bh*SS*HD;
  const float* biasrow = bias_t + (bh*SS + (size_t)(i0+row))*SS;

  for (int jt = 0; jt < 12; jt++) {
    int j0 = jt*64;
    __syncthreads();
    for (int f = t; f < 64*12; f += 256) {
      int jr = f/12, dc = (f - jr*12)*4;
      float4 kv = *(const float4*)(kbase + (size_t)(j0+jr)*HD + dc);
      kT[dc+0][jr] = kv.x; kT[dc+1][jr] = kv.y; kT[dc+2][jr] = kv.z; kT[dc+3][jr] = kv.w;
      *(float4*)&v_lds[jr][dc] = *(const float4*)(vbase + (size_t)(j0+jr)*HD + dc);
    }
    __syncthreads();

    float sacc[16];
#pragma unroll
    for (int jj4=0;jj4<4;jj4++){
      float4 b4 = *(const float4*)(biasrow + j0 + quad*16 + jj4*4);
      sacc[jj4*4+0]=b4.x; sacc[jj4*4+1]=b4.y; sacc[jj4*4+2]=b4.z; sacc[jj4*4+3]=b4.w;
    }
#pragma unroll 4
    for (int d=0; d<48; d++){
      float qv = q_lds[row][d];
#pragma unroll
      for (int jj4=0;jj4<4;jj4++){
        float4 k4 = *(float4*)&kT[d][quad*16 + jj4*4];
        sacc[jj4*4+0] = fmaf(qv, k4.x, sacc[jj4*4+0]);
        sacc[jj4*4+1] = fmaf(qv, k4.y, sacc[jj4*4+1]);
        sacc[jj4*4+2] = fmaf(qv, k4.z, sacc[jj4*4+2]);
        sacc[jj4*4+3] = fmaf(qv, k4.w, sacc[jj4*4+3]);
      }
    }
    float mx = sacc[0];
#pragma unroll
    for (int jj=1;jj<16;jj++) mx = fmaxf(mx, sacc[jj]);
    mx = fmaxf(mx, __shfl_xor(mx, 16));
    mx = fmaxf(mx, __shfl_xor(mx, 32));
    float m_new = fmaxf(m_i, mx);
    float alpha = expf(m_i - m_new);   // first iter: exp(-inf)=0
    m_i = m_new;
    float psum = 0.f;
#pragma unroll
    for (int jj=0;jj<16;jj++){ float p = expf(sacc[jj]-m_new); sacc[jj]=p; psum += p; }
    psum += __shfl_xor(psum, 16); psum += __shfl_xor(psum, 32);
    l_i = fmaf(l_i, alpha, psum);
#pragma unroll
    for (int ii=0;ii<12;ii++) oacc[ii] *= alpha;
#pragma unroll
    for (int jj=0;jj<16;jj++) p_lds[w][quad*16+jj][r] = sacc[jj];
    // same-wave LDS produce->consume: in-order DS pipe, no barrier needed
    for (int j=0;j<64;j++){
      float pv = p_lds[w][j][r];
      const float* vr = &v_lds[j][quad*12];
      float4 v0 = *(const float4*)(vr);
      float4 v1 = *(const float4*)(vr+4);
      float4 v2 = *(const float4*)(vr+8);
      oacc[0]=fmaf(pv,v0.x,oacc[0]); oacc[1]=fmaf(pv,v0.y,oacc[1]);
      oacc[2]=fmaf(pv,v0.z,oacc[2]); oacc[3]=fmaf(pv,v0.w,oacc[3]);
      oacc[4]=fmaf(pv,v1.x,oacc[4]); oacc[5]=fmaf(pv,v1.y,oacc[5]);
      oacc[6]=fmaf(pv,v1.z,oacc[6]); oacc[7]=fmaf(pv,v1.w,oacc[7]);
      oacc[8]=fmaf(pv,v2.x,oacc[8]); oacc[9]=fmaf(pv,v2.y,oacc[9]);
      oacc[10]=fmaf(pv,v2.z,oacc[10]); oacc[11]=fmaf(pv,v2.w,oacc[11]);
    }
  }
  float inv = 1.f/l_i;
  float* ob = o_ws + (bh*SS + (size_t)(i0+row))*HD + quad*12;
  float4 r0 = make_float4(oacc[0]*inv, oacc[1]*inv, oacc[2]*inv, oacc[3]*inv);
  float4 r1 = make_float4(oacc[4]*inv, oacc[5]*inv, oacc[6]*inv, oacc[7]*inv);
  float4 r2 = make_float4(oacc[8]*inv, oacc[9]*inv, oacc[10]*inv, oacc[11]*inv);
  *(float4*)(ob+0) = r0;
  *(float4*)(ob+4) = r1;
  *(float4*)(ob+8) = r2;
}

// ---------------------------------------------------------------------------
extern "C" void kernel_launch(void* const* d_in, const int* in_sizes, int n_in,
                              void* d_out, int out_size, void* d_ws, size_t ws_size,
                              hipStream_t stream)
{
  const float* a       = (const float*)d_in[0];
  const float* s       = (const float*)d_in[1];
  const float* z       = (const float*)d_in[2];
  const float* beta    = (const float*)d_in[3];
  const float* gamma_s = (const float*)d_in[4];
  const float* Wada_g  = (const float*)d_in[5];
  const float* bada_g  = (const float*)d_in[6];
  const float* Wada_o  = (const float*)d_in[7];
  const float* Wq      = (const float*)d_in[8];
  const float* bq      = (const float*)d_in[9];
  const float* Wk      = (const float*)d_in[10];
  const float* Wv      = (const float*)d_in[11];
  const float* Wb      = (const float*)d_in[12];
  const float* gz      = (const float*)d_in[13];
  const float* bz      = (const float*)d_in[14];
  const float* Wg      = (const float*)d_in[15];
  const float* Wout    = (const float*)d_in[16];
  const float* Wsg     = (const float*)d_in[17];
  const float* bsg     = (const float*)d_in[18];

  float* ws = (float*)d_ws;
  float* sn     = ws;                            // 1536*384
  float* lna    = sn   + (size_t)NROW*CS;        // 1536*768
  float* an     = lna  + (size_t)NROW*CA;        // 1536*768
  float* gate   = an   + (size_t)NROW*CA;        // 1536*768
  float* q_ws   = gate + (size_t)NROW*CA;        // [b,h,i,d]
  float* k_ws   = q_ws + (size_t)NROW*CA;
  float* v_ws   = k_ws + (size_t)NROW*CA;
  float* g_ws   = v_ws + (size_t)NROW*CA;
  float* o_ws   = g_ws + (size_t)NROW*CA;
  float* bias_t = o_ws + (size_t)NROW*CA;        // 2*16*768*768

  float* outp = (float*)d_out;

  // pair-bias first: longest kernel, no deps on the small path
  bias_kernel<<<dim3(48,48,2), 256, 0, stream>>>(z, beta, Wb, gz, bz, bias_t);

  ln_kernel<<<NROW, 256, 0, stream>>>(s, a, gamma_s, sn, lna);

  // modes 0 (ADA) + 1 (GATE)
  gemm_kernel<<<dim3(12,24,2), 256, 0, stream>>>(0,
      sn, s, an, g_ws, o_ws, lna, gate,
      Wada_g, Wada_o, bada_g, Wsg, bsg, Wq, bq, Wk, Wv, Wg, Wout,
      an, gate, q_ws, k_ws, v_ws, g_ws, outp);

  // modes 2..5 (Q,K,V,G)
  gemm_kernel<<<dim3(12,24,4), 256, 0, stream>>>(2,
      sn, s, an, g_ws, o_ws, lna, gate,
      Wada_g, Wada_o, bada_g, Wsg, bsg, Wq, bq, Wk, Wv, Wg, Wout,
      an, gate, q_ws, k_ws, v_ws, g_ws, outp);

  attn_kernel<<<dim3(12,16,2), 256, 0, stream>>>(q_ws, k_ws, v_ws, bias_t, o_ws);

  // mode 6 (final projection + sigmoid gate)
  gemm_kernel<<<dim3(12,24,1), 256, 0, stream>>>(6,
      sn, s, an, g_ws, o_ws, lna, gate,
      Wada_g, Wada_o, bada_g, Wsg, bsg, Wq, bq, Wk, Wv, Wg, Wout,
      an, gate, q_ws, k_ws, v_ws, g_ws, outp);
}